// Round 1
// baseline (366.768 us; speedup 1.0000x reference)
//
#include <hip/hip_runtime.h>

#define IN_F 128
#define OUT_F 128

// ---------------- GEMM: C[N,128] = A[N,128] @ W[128,128] (fp32) ----------------
__global__ __launch_bounds__(256) void gemm64x128(
    const float* __restrict__ A, const float* __restrict__ W,
    float* __restrict__ C, int nrows)
{
    __shared__ float As[64][65];     // +1 pad: conflict-free column reads
    __shared__ float Ws[64][128];
    const int t  = threadIdx.x;
    const int rg = t >> 4;           // 0..15 row group (4 rows each)
    const int c0 = (t & 15) * 8;     // 8 output cols per thread
    const int rowBase = blockIdx.x * 64;

    float acc[4][8];
#pragma unroll
    for (int i = 0; i < 4; ++i)
#pragma unroll
        for (int j = 0; j < 8; ++j) acc[i][j] = 0.f;

    for (int p = 0; p < 2; ++p) {    // two K-phases of 64
        // stage A tile: 64 rows x 64 k  (1024 float4)
#pragma unroll
        for (int i = 0; i < 4; ++i) {
            int q  = t + i * 256;
            int r  = q >> 4;
            int k4 = (q & 15) * 4;
            int gr = rowBase + r;
            if (gr >= nrows) gr = nrows - 1;   // clamp (values unused on write)
            const float4 v = *(const float4*)(A + (size_t)gr * IN_F + p * 64 + k4);
            As[r][k4 + 0] = v.x; As[r][k4 + 1] = v.y;
            As[r][k4 + 2] = v.z; As[r][k4 + 3] = v.w;
        }
        // stage W tile: 64 k x 128 cols (2048 float4)
#pragma unroll
        for (int i = 0; i < 8; ++i) {
            int q  = t + i * 256;
            int k  = q >> 5;
            int c4 = (q & 31) * 4;
            *(float4*)(&Ws[k][c4]) = *(const float4*)(W + (p * 64 + k) * OUT_F + c4);
        }
        __syncthreads();

#pragma unroll 4
        for (int k = 0; k < 64; ++k) {
            float a0 = As[rg * 4 + 0][k];
            float a1 = As[rg * 4 + 1][k];
            float a2 = As[rg * 4 + 2][k];
            float a3 = As[rg * 4 + 3][k];
            float4 w0 = *(const float4*)(&Ws[k][c0]);
            float4 w1 = *(const float4*)(&Ws[k][c0 + 4]);
            float wv[8] = {w0.x, w0.y, w0.z, w0.w, w1.x, w1.y, w1.z, w1.w};
            float av[4] = {a0, a1, a2, a3};
#pragma unroll
            for (int i = 0; i < 4; ++i)
#pragma unroll
                for (int j = 0; j < 8; ++j)
                    acc[i][j] = fmaf(av[i], wv[j], acc[i][j]);
        }
        __syncthreads();
    }

#pragma unroll
    for (int i = 0; i < 4; ++i) {
        int gr = rowBase + rg * 4 + i;
        if (gr < nrows) {
            float4 o0 = {acc[i][0], acc[i][1], acc[i][2], acc[i][3]};
            float4 o1 = {acc[i][4], acc[i][5], acc[i][6], acc[i][7]};
            *(float4*)(C + (size_t)gr * OUT_F + c0)     = o0;
            *(float4*)(C + (size_t)gr * OUT_F + c0 + 4) = o1;
        }
    }
}

// ---------------- CSR build ----------------
__global__ void zero_kernel(int* __restrict__ cnt, int N)
{
    int i = blockIdx.x * 256 + threadIdx.x;
    if (i < N) cnt[i] = 0;
}

__global__ void hist_kernel(const int* __restrict__ row, int* __restrict__ cnt, int E)
{
    int i = blockIdx.x * 256 + threadIdx.x;
    if (i < E) atomicAdd(&cnt[row[i]], 1);
}

// single block, 1024 threads: chunked serial scan + block scan of thread sums.
__global__ __launch_bounds__(1024) void scan_kernel(int* __restrict__ cnt,
                                                    int* __restrict__ offs, int N)
{
    __shared__ int s[1024];
    const int t = threadIdx.x;
    const int chunk = (N + 1023) >> 10;
    const int lo = t * chunk;
    const int hi = (lo + chunk < N) ? lo + chunk : N;
    int sum = 0;
    for (int i = lo; i < hi; ++i) sum += cnt[i];
    s[t] = sum;
    __syncthreads();
    for (int o = 1; o < 1024; o <<= 1) {
        int x = (t >= o) ? s[t - o] : 0;
        __syncthreads();
        s[t] += x;
        __syncthreads();
    }
    int run = s[t] - sum;             // exclusive prefix for this chunk
    for (int i = lo; i < hi; ++i) {
        int v = cnt[i];
        offs[i] = run;
        cnt[i]  = run;                // cursor for scatter
        run += v;
    }
    if (t == 0) offs[N] = s[1023];
}

__global__ void scatter_kernel(const int* __restrict__ row, int* __restrict__ cur,
                               int* __restrict__ eidx, int E)
{
    int i = blockIdx.x * 256 + threadIdx.x;
    if (i < E) {
        int p = atomicAdd(&cur[row[i]], 1);
        eidx[p] = i;
    }
}

// ---------------- SpMM + FiLM + bias + residual + PReLU ----------------
// one wave (64 lanes) per node; each lane owns 2 features (float2)
__global__ __launch_bounds__(256) void spmm_film_kernel(
    const int* __restrict__ offs, const int* __restrict__ eidx,
    const float* __restrict__ ew, const int* __restrict__ ecol,
    const float* __restrict__ seq_fts, const int* __restrict__ ntype,
    const float* __restrict__ Wg, const float* __restrict__ bg,
    const float* __restrict__ Wb, const float* __restrict__ bb,
    const float* __restrict__ bias, const float* __restrict__ prelu,
    float* __restrict__ out, int N)
{
    const int wid  = (blockIdx.x * blockDim.x + threadIdx.x) >> 6;  // node id
    const int lane = threadIdx.x & 63;
    if (wid >= N) return;
    const int f0 = lane * 2;

    const int s = offs[wid];
    const int e = offs[wid + 1];
    float ax = 0.f, ay = 0.f;
    for (int i = s; i < e; ++i) {
        int   ed = eidx[i];
        float w  = ew[ed];
        int   c  = ecol[ed];
        float2 v = *(const float2*)(seq_fts + (size_t)c * OUT_F + f0);
        ax = fmaf(w, v.x, ax);
        ay = fmaf(w, v.y, ay);
    }

    const int tp = ntype[wid];
    float gx = Wg[tp * OUT_F + f0]     + bg[f0];
    float gy = Wg[tp * OUT_F + f0 + 1] + bg[f0 + 1];
    float px = Wb[tp * OUT_F + f0]     + bb[f0];
    float py = Wb[tp * OUT_F + f0 + 1] + bb[f0 + 1];
    float2 sf = *(const float2*)(seq_fts + (size_t)wid * OUT_F + f0);

    float ox = fmaf(gx, ax, px) + bias[f0]     + sf.x;
    float oy = fmaf(gy, ay, py) + bias[f0 + 1] + sf.y;
    float sl = prelu[0];
    ox = (ox >= 0.f) ? ox : sl * ox;
    oy = (oy >= 0.f) ? oy : sl * oy;
    *(float2*)(out + (size_t)wid * OUT_F + f0) = make_float2(ox, oy);
}

// ---------------- launch ----------------
extern "C" void kernel_launch(void* const* d_in, const int* in_sizes, int n_in,
                              void* d_out, int out_size, void* d_ws, size_t ws_size,
                              hipStream_t stream)
{
    const float* seq   = (const float*)d_in[0];
    const float* ew    = (const float*)d_in[1];
    const float* W_fc  = (const float*)d_in[2];
    const float* W_g   = (const float*)d_in[3];
    const float* b_g   = (const float*)d_in[4];
    const float* W_b   = (const float*)d_in[5];
    const float* b_b   = (const float*)d_in[6];
    const float* bias  = (const float*)d_in[7];
    const float* prelu = (const float*)d_in[8];
    const int*   erow  = (const int*)d_in[9];
    const int*   ecol  = (const int*)d_in[10];
    const int*   ntype = (const int*)d_in[11];
    const int N = in_sizes[11];
    const int E = in_sizes[1];

    char* ws = (char*)d_ws;
    size_t o = 0;
    float* seq_fts = (float*)(ws + o); o += (size_t)N * OUT_F * sizeof(float); o = (o + 15) & ~(size_t)15;
    int*   cnt     = (int*)(ws + o);   o += (size_t)N * sizeof(int);           o = (o + 15) & ~(size_t)15;
    int*   offs    = (int*)(ws + o);   o += ((size_t)N + 1) * sizeof(int);     o = (o + 15) & ~(size_t)15;
    int*   eidx    = (int*)(ws + o);   o += (size_t)E * sizeof(int);

    hipLaunchKernelGGL(zero_kernel, dim3((N + 255) / 256), dim3(256), 0, stream, cnt, N);
    hipLaunchKernelGGL(hist_kernel, dim3((E + 255) / 256), dim3(256), 0, stream, erow, cnt, E);
    hipLaunchKernelGGL(scan_kernel, dim3(1), dim3(1024), 0, stream, cnt, offs, N);
    hipLaunchKernelGGL(scatter_kernel, dim3((E + 255) / 256), dim3(256), 0, stream, erow, cnt, eidx, E);
    hipLaunchKernelGGL(gemm64x128, dim3((N + 63) / 64), dim3(256), 0, stream, seq, W_fc, seq_fts, N);
    hipLaunchKernelGGL(spmm_film_kernel, dim3((N + 3) / 4), dim3(256), 0, stream,
                       offs, eidx, ew, ecol, seq_fts, ntype,
                       W_g, b_g, W_b, b_b, bias, prelu, (float*)d_out, N);
}

// Round 2
// 174.481 us; speedup vs baseline: 2.1021x; 2.1021x over previous
//
#include <hip/hip_runtime.h>

#define IN_F 128
#define OUT_F 128

static __device__ __forceinline__ unsigned f2bf(float x) {
    unsigned b = __float_as_uint(x);
    return (b + 0x7FFFu + ((b >> 16) & 1u)) >> 16;   // RNE
}
static __device__ __forceinline__ float bf2f(unsigned short u) {
    return __uint_as_float(((unsigned)u) << 16);
}

// ---------------- GEMM: seq_b16[N,128] = bf16( A[N,128] @ W[128,128] ) ----------------
__global__ __launch_bounds__(256) void gemm64x128(
    const float* __restrict__ A, const float* __restrict__ W,
    unsigned short* __restrict__ Cb, int nrows)
{
    __shared__ float As[64][65];     // +1 pad: conflict-free column reads
    __shared__ float Ws[64][128];
    const int t  = threadIdx.x;
    const int rg = t >> 4;           // 0..15 row group (4 rows each)
    const int c0 = (t & 15) * 8;     // 8 output cols per thread
    const int rowBase = blockIdx.x * 64;

    float acc[4][8];
#pragma unroll
    for (int i = 0; i < 4; ++i)
#pragma unroll
        for (int j = 0; j < 8; ++j) acc[i][j] = 0.f;

    for (int p = 0; p < 2; ++p) {    // two K-phases of 64
#pragma unroll
        for (int i = 0; i < 4; ++i) {
            int q  = t + i * 256;
            int r  = q >> 4;
            int k4 = (q & 15) * 4;
            int gr = rowBase + r;
            if (gr >= nrows) gr = nrows - 1;
            const float4 v = *(const float4*)(A + (size_t)gr * IN_F + p * 64 + k4);
            As[r][k4 + 0] = v.x; As[r][k4 + 1] = v.y;
            As[r][k4 + 2] = v.z; As[r][k4 + 3] = v.w;
        }
#pragma unroll
        for (int i = 0; i < 8; ++i) {
            int q  = t + i * 256;
            int k  = q >> 5;
            int c4 = (q & 31) * 4;
            *(float4*)(&Ws[k][c4]) = *(const float4*)(W + (p * 64 + k) * OUT_F + c4);
        }
        __syncthreads();

#pragma unroll 4
        for (int k = 0; k < 64; ++k) {
            float av[4] = {As[rg * 4 + 0][k], As[rg * 4 + 1][k],
                           As[rg * 4 + 2][k], As[rg * 4 + 3][k]};
            float4 w0 = *(const float4*)(&Ws[k][c0]);
            float4 w1 = *(const float4*)(&Ws[k][c0 + 4]);
            float wv[8] = {w0.x, w0.y, w0.z, w0.w, w1.x, w1.y, w1.z, w1.w};
#pragma unroll
            for (int i = 0; i < 4; ++i)
#pragma unroll
                for (int j = 0; j < 8; ++j)
                    acc[i][j] = fmaf(av[i], wv[j], acc[i][j]);
        }
        __syncthreads();
    }

#pragma unroll
    for (int i = 0; i < 4; ++i) {
        int gr = rowBase + rg * 4 + i;
        if (gr < nrows) {
            uint4 pk;
            pk.x = f2bf(acc[i][0]) | (f2bf(acc[i][1]) << 16);
            pk.y = f2bf(acc[i][2]) | (f2bf(acc[i][3]) << 16);
            pk.z = f2bf(acc[i][4]) | (f2bf(acc[i][5]) << 16);
            pk.w = f2bf(acc[i][6]) | (f2bf(acc[i][7]) << 16);
            *(uint4*)(Cb + (size_t)gr * OUT_F + c0) = pk;
        }
    }
}

// ---------------- CSR build ----------------
__global__ void zero_kernel(int* __restrict__ cnt, int N)
{
    int i = blockIdx.x * 256 + threadIdx.x;
    if (i < N) cnt[i] = 0;
}

__global__ void hist_kernel(const int* __restrict__ row, int* __restrict__ cnt, int E)
{
    int i = (blockIdx.x * 256 + threadIdx.x) * 4;
    if (i + 3 < E) {
        int4 r = *(const int4*)(row + i);
        atomicAdd(&cnt[r.x], 1); atomicAdd(&cnt[r.y], 1);
        atomicAdd(&cnt[r.z], 1); atomicAdd(&cnt[r.w], 1);
    } else {
        for (; i < E; ++i) atomicAdd(&cnt[row[i]], 1);
    }
}

// phase A: per-block sums of cnt
__global__ __launch_bounds__(256) void scanA_kernel(const int* __restrict__ cnt,
                                                    int* __restrict__ bsum, int N)
{
    __shared__ int ws[4];
    int i = blockIdx.x * 256 + threadIdx.x;
    int v = (i < N) ? cnt[i] : 0;
    int s = v;
#pragma unroll
    for (int o = 32; o > 0; o >>= 1) s += __shfl_down(s, o, 64);
    if ((threadIdx.x & 63) == 0) ws[threadIdx.x >> 6] = s;
    __syncthreads();
    if (threadIdx.x == 0) bsum[blockIdx.x] = ws[0] + ws[1] + ws[2] + ws[3];
}

// phase B: single block exclusive-scans the (<=1024) block sums
__global__ __launch_bounds__(1024) void scanB_kernel(const int* __restrict__ bsum,
                                                     int* __restrict__ boff, int NB)
{
    __shared__ int s[1024];
    int t = threadIdx.x;
    int v = (t < NB) ? bsum[t] : 0;
    s[t] = v;
    __syncthreads();
    for (int o = 1; o < 1024; o <<= 1) {
        int x = (t >= o) ? s[t - o] : 0;
        __syncthreads();
        s[t] += x;
        __syncthreads();
    }
    if (t < NB) boff[t] = s[t] - v;   // exclusive
}

// phase C: per-block exclusive scan + base, write offs[] and cursor cur[]
__global__ __launch_bounds__(256) void scanC_kernel(const int* __restrict__ cnt,
                                                    const int* __restrict__ boff,
                                                    int* __restrict__ offs,
                                                    int* __restrict__ cur, int N)
{
    __shared__ int s[256];
    int t = threadIdx.x;
    int i = blockIdx.x * 256 + t;
    int v = (i < N) ? cnt[i] : 0;
    s[t] = v;
    __syncthreads();
    for (int o = 1; o < 256; o <<= 1) {
        int x = (t >= o) ? s[t - o] : 0;
        __syncthreads();
        s[t] += x;
        __syncthreads();
    }
    if (i < N) {
        int off = boff[blockIdx.x] + s[t] - v;  // exclusive
        offs[i] = off;
        cur[i]  = off;
        if (i == N - 1) offs[N] = off + v;
    }
}

// scatter packed (weight, col) sorted by row
__global__ void scatter_kernel(const int* __restrict__ row, const int* __restrict__ col,
                               const float* __restrict__ ew, int* __restrict__ cur,
                               float2* __restrict__ wcv, int E)
{
    int i = blockIdx.x * 256 + threadIdx.x;
    if (i < E) {
        int p = atomicAdd(&cur[row[i]], 1);
        wcv[p] = make_float2(ew[i], __int_as_float(col[i]));
    }
}

// ---------------- SpMM(bf16 gather) + FiLM + bias + residual + PReLU ----------------
// half-wave (32 lanes) per node; each lane owns 4 features (8 B bf16 gather)
__global__ __launch_bounds__(256) void spmm_film_kernel(
    const int* __restrict__ offs, const float2* __restrict__ wcv,
    const unsigned short* __restrict__ seqb, const int* __restrict__ ntype,
    const float* __restrict__ Wg, const float* __restrict__ bg,
    const float* __restrict__ Wb, const float* __restrict__ bb,
    const float* __restrict__ bias, const float* __restrict__ prelu,
    float* __restrict__ out, int N)
{
    const int gtid = blockIdx.x * 256 + threadIdx.x;
    const int wave = gtid >> 6;
    const int lane = threadIdx.x & 63;
    const int sub  = lane >> 5;
    const int fl   = lane & 31;
    const int f0   = fl * 4;
    const int node = wave * 2 + sub;
    if (node >= N) return;

    const int s = offs[node];
    const int e = offs[node + 1];
    float a0 = 0.f, a1 = 0.f, a2 = 0.f, a3 = 0.f;
    int i = s;
    for (; i + 2 <= e; i += 2) {
        float2 p = wcv[i];
        float2 q = wcv[i + 1];
        int c0i = __float_as_int(p.y);
        int c1i = __float_as_int(q.y);
        ushort4 r0 = *(const ushort4*)(seqb + (size_t)c0i * OUT_F + f0);
        ushort4 r1 = *(const ushort4*)(seqb + (size_t)c1i * OUT_F + f0);
        a0 = fmaf(p.x, bf2f(r0.x), a0); a1 = fmaf(p.x, bf2f(r0.y), a1);
        a2 = fmaf(p.x, bf2f(r0.z), a2); a3 = fmaf(p.x, bf2f(r0.w), a3);
        a0 = fmaf(q.x, bf2f(r1.x), a0); a1 = fmaf(q.x, bf2f(r1.y), a1);
        a2 = fmaf(q.x, bf2f(r1.z), a2); a3 = fmaf(q.x, bf2f(r1.w), a3);
    }
    if (i < e) {
        float2 p = wcv[i];
        int c0i = __float_as_int(p.y);
        ushort4 r0 = *(const ushort4*)(seqb + (size_t)c0i * OUT_F + f0);
        a0 = fmaf(p.x, bf2f(r0.x), a0); a1 = fmaf(p.x, bf2f(r0.y), a1);
        a2 = fmaf(p.x, bf2f(r0.z), a2); a3 = fmaf(p.x, bf2f(r0.w), a3);
    }

    const int tp = ntype[node];
    float4 g  = *(const float4*)(Wg + tp * OUT_F + f0);
    float4 gb = *(const float4*)(bg + f0);
    float4 bt = *(const float4*)(Wb + tp * OUT_F + f0);
    float4 bv = *(const float4*)(bb + f0);
    float4 bs = *(const float4*)(bias + f0);
    ushort4 rs = *(const ushort4*)(seqb + (size_t)node * OUT_F + f0);
    float sl = prelu[0];

    float o0 = fmaf(g.x + gb.x, a0, bt.x + bv.x) + bs.x + bf2f(rs.x);
    float o1 = fmaf(g.y + gb.y, a1, bt.y + bv.y) + bs.y + bf2f(rs.y);
    float o2 = fmaf(g.z + gb.z, a2, bt.z + bv.z) + bs.z + bf2f(rs.z);
    float o3 = fmaf(g.w + gb.w, a3, bt.w + bv.w) + bs.w + bf2f(rs.w);
    o0 = (o0 >= 0.f) ? o0 : sl * o0;
    o1 = (o1 >= 0.f) ? o1 : sl * o1;
    o2 = (o2 >= 0.f) ? o2 : sl * o2;
    o3 = (o3 >= 0.f) ? o3 : sl * o3;
    *(float4*)(out + (size_t)node * OUT_F + f0) = make_float4(o0, o1, o2, o3);
}

// ---------------- launch ----------------
extern "C" void kernel_launch(void* const* d_in, const int* in_sizes, int n_in,
                              void* d_out, int out_size, void* d_ws, size_t ws_size,
                              hipStream_t stream)
{
    const float* seq   = (const float*)d_in[0];
    const float* ew    = (const float*)d_in[1];
    const float* W_fc  = (const float*)d_in[2];
    const float* W_g   = (const float*)d_in[3];
    const float* b_g   = (const float*)d_in[4];
    const float* W_b   = (const float*)d_in[5];
    const float* b_b   = (const float*)d_in[6];
    const float* bias  = (const float*)d_in[7];
    const float* prelu = (const float*)d_in[8];
    const int*   erow  = (const int*)d_in[9];
    const int*   ecol  = (const int*)d_in[10];
    const int*   ntype = (const int*)d_in[11];
    const int N = in_sizes[11];
    const int E = in_sizes[1];
    const int NB = (N + 255) / 256;

    char* ws = (char*)d_ws;
    size_t o = 0;
    unsigned short* seqb = (unsigned short*)(ws + o); o += (size_t)N * OUT_F * 2; o = (o + 15) & ~(size_t)15;
    int*    cnt  = (int*)(ws + o);    o += (size_t)N * 4;        o = (o + 15) & ~(size_t)15;
    int*    offs = (int*)(ws + o);    o += ((size_t)N + 1) * 4;  o = (o + 15) & ~(size_t)15;
    int*    cur  = (int*)(ws + o);    o += (size_t)N * 4;        o = (o + 15) & ~(size_t)15;
    int*    bsum = (int*)(ws + o);    o += 1024 * 4;
    int*    boff = (int*)(ws + o);    o += 1024 * 4;
    float2* wcv  = (float2*)(ws + o); o += (size_t)E * 8;

    hipLaunchKernelGGL(zero_kernel, dim3(NB), dim3(256), 0, stream, cnt, N);
    hipLaunchKernelGGL(hist_kernel, dim3((E / 4 + 255) / 256 + 1), dim3(256), 0, stream, erow, cnt, E);
    hipLaunchKernelGGL(scanA_kernel, dim3(NB), dim3(256), 0, stream, cnt, bsum, N);
    hipLaunchKernelGGL(scanB_kernel, dim3(1), dim3(1024), 0, stream, bsum, boff, NB);
    hipLaunchKernelGGL(scanC_kernel, dim3(NB), dim3(256), 0, stream, cnt, boff, offs, cur, N);
    hipLaunchKernelGGL(scatter_kernel, dim3((E + 255) / 256), dim3(256), 0, stream, erow, ecol, ew, cur, wcv, E);
    hipLaunchKernelGGL(gemm64x128, dim3((N + 63) / 64), dim3(256), 0, stream, seq, W_fc, seqb, N);
    hipLaunchKernelGGL(spmm_film_kernel, dim3((N / 2 + 3) / 4 + 1), dim3(256), 0, stream,
                       offs, wcv, seqb, ntype, W_g, b_g, W_b, b_b, bias, prelu, (float*)d_out, N);
}